// Round 3
// baseline (4240.534 us; speedup 1.0000x reference)
//
#include <hip/hip_runtime.h>

#define HID 128
#define NPB1 16   // nodes per block, linear1
#define SCAN_B 256

// ---------------- index dtype detection + conversion ----------------
__global__ void detect_kernel(const unsigned int* __restrict__ p, int* __restrict__ flag) {
    if (threadIdx.x == 0 && blockIdx.x == 0) {
        int is64 = 1;
        for (int i = 0; i < 64; ++i) {
            if (p[2 * i + 1] != 0u) { is64 = 0; break; }
        }
        *flag = is64;
    }
}

__global__ void cvt_kernel(const void* __restrict__ p, int* __restrict__ out, int n,
                           const int* __restrict__ flag) {
    int i = blockIdx.x * blockDim.x + threadIdx.x;
    if (i < n) {
        out[i] = (*flag) ? (int)((const long long*)p)[i] : ((const int*)p)[i];
    }
}

// ---------------- zeroing (graph-capture-safe, no memset) ----------------
__global__ void zero_kernel(float4* __restrict__ p, long long n4) {
    long long i = (long long)blockIdx.x * blockDim.x + threadIdx.x;
    long long stride = (long long)gridDim.x * blockDim.x;
    for (; i < n4; i += stride) p[i] = make_float4(0.f, 0.f, 0.f, 0.f);
}

// ---------------- degree + dinv ----------------
__global__ void deg_kernel(const int* __restrict__ dst, int* __restrict__ deg, int E) {
    int i = blockIdx.x * blockDim.x + threadIdx.x;
    if (i < E) atomicAdd(&deg[dst[i]], 1);
}

__global__ void dinv_kernel(const int* __restrict__ deg, float* __restrict__ dinv, int N) {
    int i = blockIdx.x * blockDim.x + threadIdx.x;
    if (i < N) dinv[i] = rsqrtf((float)(deg[i] + 1));  // +1 = self loop
}

// ---------------- exclusive scan (3 kernels) ----------------
__global__ __launch_bounds__(SCAN_B) void scan1_kernel(const int* __restrict__ deg,
                                                       int* __restrict__ incl,
                                                       int* __restrict__ blockSums, int N) {
    __shared__ int s[SCAN_B];
    int i = blockIdx.x * SCAN_B + threadIdx.x;
    int v = (i < N) ? deg[i] : 0;
    s[threadIdx.x] = v;
    __syncthreads();
#pragma unroll
    for (int off = 1; off < SCAN_B; off <<= 1) {
        int t = (threadIdx.x >= off) ? s[threadIdx.x - off] : 0;
        __syncthreads();
        s[threadIdx.x] += t;
        __syncthreads();
    }
    if (i < N) incl[i] = s[threadIdx.x];
    if (threadIdx.x == SCAN_B - 1) blockSums[blockIdx.x] = s[SCAN_B - 1];
}

__global__ __launch_bounds__(1024) void scan2_kernel(int* __restrict__ blockSums, int nb) {
    __shared__ int s[1024];
    int v = (threadIdx.x < nb) ? blockSums[threadIdx.x] : 0;
    s[threadIdx.x] = v;
    __syncthreads();
#pragma unroll
    for (int off = 1; off < 1024; off <<= 1) {
        int t = (threadIdx.x >= off) ? s[threadIdx.x - off] : 0;
        __syncthreads();
        s[threadIdx.x] += t;
        __syncthreads();
    }
    if (threadIdx.x < nb) blockSums[threadIdx.x] = (threadIdx.x > 0) ? s[threadIdx.x - 1] : 0;
}

__global__ void scan3_kernel(const int* __restrict__ incl, const int* __restrict__ deg,
                             const int* __restrict__ blockSums, int* __restrict__ rowstart,
                             int N, int E) {
    int i = blockIdx.x * blockDim.x + threadIdx.x;
    if (i < N) rowstart[i] = incl[i] - deg[i] + blockSums[i / SCAN_B];
    if (i == 0) rowstart[N] = E;
}

// ---------------- counting-sort scatter: elist[pos] = (src, norm) ----------------
__global__ void scatter_kernel(const int* __restrict__ src, const int* __restrict__ dst,
                               const int* __restrict__ rowstart, int* __restrict__ cursor,
                               int2* __restrict__ elist, const float* __restrict__ dinv, int E) {
    int e = blockIdx.x * blockDim.x + threadIdx.x;
    if (e >= E) return;
    int s = src[e], d = dst[e];
    int pos = rowstart[d] + atomicAdd(&cursor[d], 1);
    float nm = dinv[s] * dinv[d];
    elist[pos] = make_int2(s, __float_as_int(nm));
}

// ---------------- linear1: h = x @ W1   (x: [N,20], W1: [20,128]) ----------------
__global__ __launch_bounds__(HID) void linear1_kernel(const float* __restrict__ x,
                                                      const float* __restrict__ W,
                                                      float* __restrict__ h, int N, int IN) {
    __shared__ float Ws[20 * HID];
    __shared__ float xs[NPB1][20];
    for (int i = threadIdx.x; i < IN * HID; i += blockDim.x) Ws[i] = W[i];
    int n0 = blockIdx.x * NPB1;
    for (int i = threadIdx.x; i < NPB1 * IN; i += blockDim.x) {
        int m = i / IN, k = i % IN;
        int n = n0 + m;
        xs[m][k] = (n < N) ? x[(size_t)n * IN + k] : 0.f;
    }
    __syncthreads();
    int j = threadIdx.x;
    for (int m = 0; m < NPB1; ++m) {
        int n = n0 + m;
        if (n >= N) break;
        float acc = 0.f;
#pragma unroll 20
        for (int k = 0; k < 20; ++k) acc += xs[m][k] * Ws[k * HID + j];
        h[(size_t)n * HID + j] = acc;
    }
}

// ---------------- linear2: register-tiled GEMM  C[N,128] = A[N,128] @ W[128,128] ----------------
#define GBM 128
#define GBK 32
#define XS_LD 132  // GBM + 4 pad (keeps 16B alignment, spreads banks)

__global__ __launch_bounds__(256) void gemm128_kernel(const float* __restrict__ A,
                                                      const float* __restrict__ W,
                                                      float* __restrict__ C, int N) {
    __shared__ float xs[2][GBK][XS_LD];   // k-major, node-minor (transposed)
    __shared__ float wsh[2][GBK][HID];    // k-major, col-minor
    const int tid = threadIdx.x;
    const int n0 = blockIdx.x * GBM;
    const int ttx = tid & 15;    // col group  -> cols ttx*8 .. +7
    const int tty = tid >> 4;    // node group -> nodes tty*8 .. +7
    const int sx_node = tid >> 3;  // 0..31
    const int sx_kv   = tid & 7;   // 0..7 : float4 over k
    const int sw_k    = tid >> 5;  // 0..7
    const int sw_c    = tid & 31;  // 0..31 : float4 over col

    float acc[8][8];
#pragma unroll
    for (int m = 0; m < 8; ++m)
#pragma unroll
        for (int n = 0; n < 8; ++n) acc[m][n] = 0.f;

    auto stage = [&](int buf, int k0) {
#pragma unroll
        for (int r = 0; r < 4; ++r) {
            int node = r * 32 + sx_node;
            int gn = n0 + node;
            float4 v = make_float4(0.f, 0.f, 0.f, 0.f);
            if (gn < N) v = *(const float4*)(A + (size_t)gn * HID + k0 + sx_kv * 4);
            xs[buf][sx_kv * 4 + 0][node] = v.x;
            xs[buf][sx_kv * 4 + 1][node] = v.y;
            xs[buf][sx_kv * 4 + 2][node] = v.z;
            xs[buf][sx_kv * 4 + 3][node] = v.w;
        }
#pragma unroll
        for (int r = 0; r < 4; ++r) {
            int kk = r * 8 + sw_k;
            *(float4*)&wsh[buf][kk][sw_c * 4] =
                *(const float4*)(W + (size_t)(k0 + kk) * HID + sw_c * 4);
        }
    };

    stage(0, 0);
    __syncthreads();
#pragma unroll
    for (int kc = 0; kc < 4; ++kc) {
        int cur = kc & 1;
        if (kc < 3) stage(cur ^ 1, (kc + 1) * GBK);
#pragma unroll
        for (int kk = 0; kk < GBK; ++kk) {
            float a[8], b[8];
            *(float4*)&a[0] = *(const float4*)&xs[cur][kk][tty * 8];
            *(float4*)&a[4] = *(const float4*)&xs[cur][kk][tty * 8 + 4];
            *(float4*)&b[0] = *(const float4*)&wsh[cur][kk][ttx * 8];
            *(float4*)&b[4] = *(const float4*)&wsh[cur][kk][ttx * 8 + 4];
#pragma unroll
            for (int m = 0; m < 8; ++m)
#pragma unroll
                for (int n = 0; n < 8; ++n) acc[m][n] += a[m] * b[n];
        }
        __syncthreads();
    }

#pragma unroll
    for (int m = 0; m < 8; ++m) {
        int gn = n0 + tty * 8 + m;
        if (gn < N) {
            float* cp = C + (size_t)gn * HID + ttx * 8;
            *(float4*)cp = make_float4(acc[m][0], acc[m][1], acc[m][2], acc[m][3]);
            *(float4*)(cp + 4) = make_float4(acc[m][4], acc[m][5], acc[m][6], acc[m][7]);
        }
    }
}

// ---------------- CSR aggregation fused with self-loop + bias + relu ----------------
__global__ __launch_bounds__(256) void csr_agg_kernel(const float* __restrict__ h,
                                                      float* __restrict__ outb,
                                                      const int* __restrict__ rowstart,
                                                      const int2* __restrict__ elist,
                                                      const float* __restrict__ dinv,
                                                      const float* __restrict__ bias,
                                                      int N) {
    int node = blockIdx.x * 2 + (threadIdx.x >> 7);
    if (node >= N) return;
    int j = threadIdx.x & 127;
    int beg = rowstart[node], end = rowstart[node + 1];
    float acc = 0.f;
    int e = beg;
    for (; e + 1 < end; e += 2) {
        int2 p0 = elist[e];
        int2 p1 = elist[e + 1];
        float a0 = h[(size_t)p0.x * HID + j];
        float a1 = h[(size_t)p1.x * HID + j];
        acc += a0 * __int_as_float(p0.y);
        acc += a1 * __int_as_float(p1.y);
    }
    if (e < end) {
        int2 p0 = elist[e];
        acc += h[(size_t)p0.x * HID + j] * __int_as_float(p0.y);
    }
    float di = dinv[node];
    float v = acc + h[(size_t)node * HID + j] * di * di + bias[j];
    outb[(size_t)node * HID + j] = fmaxf(v, 0.f);
}

// ---------------- pooling: segmented (batch is sorted) ----------------
__global__ void gstart_kernel(const int* __restrict__ batch, int* __restrict__ gstart,
                              int N, int G) {
    int g = blockIdx.x * blockDim.x + threadIdx.x;
    if (g > G) return;
    int lo = 0, hi = N;
    while (lo < hi) {
        int mid = (lo + hi) >> 1;
        if (batch[mid] < g) lo = mid + 1; else hi = mid;
    }
    gstart[g] = lo;
}

__global__ __launch_bounds__(256) void pool2_kernel(const float* __restrict__ h,
                                                    const int* __restrict__ gstart,
                                                    float* __restrict__ meanp, int G) {
    int g = blockIdx.x;
    int half = threadIdx.x >> 7;
    int j = threadIdx.x & 127;
    int beg = gstart[g], end = gstart[g + 1];
    float s = 0.f;
    for (int n = beg + half; n < end; n += 2) s += h[(size_t)n * HID + j];
    __shared__ float red[2][HID];
    red[half][j] = s;
    __syncthreads();
    if (half == 0) {
        float tot = red[0][j] + red[1][j];
        float c = (float)(end - beg);
        meanp[(size_t)g * HID + j] = tot / fmaxf(c, 1.f);
    }
}

// ---------------- classifier: out = meanp @ Wc + bc ----------------
#define TILE_G 32
__global__ __launch_bounds__(256) void classifier_kernel(const float* __restrict__ meanp,
                                                         const float* __restrict__ Wc,
                                                         const float* __restrict__ bc,
                                                         float* __restrict__ out, int G, int OUT) {
    __shared__ float ps[TILE_G * HID];  // 16 KiB
    int g0 = blockIdx.y * TILE_G;
    for (int i = threadIdx.x; i < TILE_G * HID; i += blockDim.x) {
        int g = g0 + (i >> 7);
        ps[i] = (g < G) ? meanp[(size_t)g * HID + (i & 127)] : 0.f;
    }
    __syncthreads();
    int o = blockIdx.x * blockDim.x + threadIdx.x;
    if (o >= OUT) return;
    float acc[TILE_G];
#pragma unroll
    for (int g = 0; g < TILE_G; ++g) acc[g] = 0.f;
    for (int k = 0; k < HID; ++k) {
        float w = Wc[(size_t)k * OUT + o];
#pragma unroll
        for (int g = 0; g < TILE_G; ++g) acc[g] += ps[g * HID + k] * w;
    }
    float b = bc[o];
    for (int g = 0; g < TILE_G && (g0 + g) < G; ++g)
        out[(size_t)(g0 + g) * OUT + o] = acc[g] + b;
}

// ---------------- launch ----------------
extern "C" void kernel_launch(void* const* d_in, const int* in_sizes, int n_in,
                              void* d_out, int out_size, void* d_ws, size_t ws_size,
                              hipStream_t stream) {
    const float* x  = (const float*)d_in[0];
    const void*  ei = d_in[1];
    const void*  bt = d_in[2];
    const float* W1 = (const float*)d_in[3];
    const float* b1 = (const float*)d_in[4];
    const float* W2 = (const float*)d_in[5];
    const float* b2 = (const float*)d_in[6];
    const float* Wc = (const float*)d_in[7];
    const float* bc = (const float*)d_in[8];
    float* out = (float*)d_out;

    const int N   = in_sizes[2];
    const int E   = in_sizes[1] / 2;
    const int IN  = in_sizes[0] / N;
    const int OUT = in_sizes[8];
    const int G   = out_size / OUT;

    // workspace layout
    char* ws = (char*)d_ws;
    size_t off = 0;
    auto alloc = [&](size_t bytes) {
        size_t p = off;
        off += (bytes + 255) & ~(size_t)255;
        return p;
    };
    int*   idx32    = (int*)(ws + alloc((size_t)2 * E * 4));
    int*   batch32  = (int*)(ws + alloc((size_t)N * 4));
    int*   deg      = (int*)(ws + alloc((size_t)N * 4));
    float* dinv     = (float*)(ws + alloc((size_t)N * 4));
    int*   incl     = (int*)(ws + alloc((size_t)N * 4));
    int*   rowstart = (int*)(ws + alloc((size_t)(N + 1) * 4));
    int*   cursor   = (int*)(ws + alloc((size_t)N * 4));
    int*   blockSums= (int*)(ws + alloc((size_t)1024 * 4));
    int2*  elist    = (int2*)(ws + alloc((size_t)E * 8));
    float* bufA     = (float*)(ws + alloc((size_t)N * HID * 4));
    float* bufB     = (float*)(ws + alloc((size_t)N * HID * 4));
    int*   gstart   = (int*)(ws + alloc((size_t)(G + 1) * 4));
    float* meanp    = (float*)(ws + alloc((size_t)G * HID * 4));
    int*   flag     = (int*)(ws + alloc(4));
    (void)ws_size;

    int* srcI = idx32;
    int* dstI = idx32 + E;

    const int B = 256;
    const int nb = (N + SCAN_B - 1) / SCAN_B;

    // 1. detect index dtype, convert to int32
    detect_kernel<<<1, 64, 0, stream>>>((const unsigned int*)ei, flag);
    cvt_kernel<<<(2 * E + B - 1) / B, B, 0, stream>>>(ei, idx32, 2 * E, flag);
    cvt_kernel<<<(N + B - 1) / B, B, 0, stream>>>(bt, batch32, N, flag);

    // 2. degrees (+1 self loop) -> dinv
    zero_kernel<<<256, B, 0, stream>>>((float4*)deg, (long long)N / 4);
    deg_kernel<<<(E + B - 1) / B, B, 0, stream>>>(dstI, deg, E);
    dinv_kernel<<<(N + B - 1) / B, B, 0, stream>>>(deg, dinv, N);

    // 3. CSR build: exclusive scan + counting-sort scatter
    scan1_kernel<<<nb, SCAN_B, 0, stream>>>(deg, incl, blockSums, N);
    scan2_kernel<<<1, 1024, 0, stream>>>(blockSums, nb);
    scan3_kernel<<<(N + B - 1) / B, B, 0, stream>>>(incl, deg, blockSums, rowstart, N, E);
    zero_kernel<<<256, B, 0, stream>>>((float4*)cursor, (long long)N / 4);
    scatter_kernel<<<(E + B - 1) / B, B, 0, stream>>>(srcI, dstI, rowstart, cursor, elist, dinv, E);

    // 4. graph boundaries for pooling
    gstart_kernel<<<2, 256, 0, stream>>>(batch32, gstart, N, G);

    // 5. layer 1
    linear1_kernel<<<(N + NPB1 - 1) / NPB1, HID, 0, stream>>>(x, W1, bufA, N, IN);
    csr_agg_kernel<<<(N + 1) / 2, 256, 0, stream>>>(bufA, bufB, rowstart, elist, dinv, b1, N);

    // 6. layer 2
    gemm128_kernel<<<(N + GBM - 1) / GBM, 256, 0, stream>>>(bufB, W2, bufA, N);
    csr_agg_kernel<<<(N + 1) / 2, 256, 0, stream>>>(bufA, bufB, rowstart, elist, dinv, b2, N);

    // 7. mean pool (segmented, no atomics)
    pool2_kernel<<<G, 256, 0, stream>>>(bufB, gstart, meanp, G);

    // 8. classifier
    {
        dim3 grid((OUT + 255) / 256, (G + TILE_G - 1) / TILE_G);
        classifier_kernel<<<grid, 256, 0, stream>>>(meanp, Wc, bc, out, G, OUT);
    }
}

// Round 4
// 760.139 us; speedup vs baseline: 5.5786x; 5.5786x over previous
//
#include <hip/hip_runtime.h>

#define HID 128
#define NPB1 16   // nodes per block, linear1
#define SCAN_B 256

// ---------------- index dtype detection + conversion ----------------
__global__ void detect_kernel(const unsigned int* __restrict__ p, int* __restrict__ flag) {
    if (threadIdx.x == 0 && blockIdx.x == 0) {
        int is64 = 1;
        for (int i = 0; i < 64; ++i) {
            if (p[2 * i + 1] != 0u) { is64 = 0; break; }
        }
        *flag = is64;
    }
}

__global__ void cvt_kernel(const void* __restrict__ p, int* __restrict__ out, int n,
                           const int* __restrict__ flag) {
    int i = blockIdx.x * blockDim.x + threadIdx.x;
    if (i < n) {
        out[i] = (*flag) ? (int)((const long long*)p)[i] : ((const int*)p)[i];
    }
}

// ---------------- zeroing (graph-capture-safe, no memset) ----------------
__global__ void zero_kernel(float4* __restrict__ p, long long n4) {
    long long i = (long long)blockIdx.x * blockDim.x + threadIdx.x;
    long long stride = (long long)gridDim.x * blockDim.x;
    for (; i < n4; i += stride) p[i] = make_float4(0.f, 0.f, 0.f, 0.f);
}

// ---------------- degree + dinv ----------------
__global__ void deg_kernel(const int* __restrict__ dst, int* __restrict__ deg, int E) {
    int i = blockIdx.x * blockDim.x + threadIdx.x;
    if (i < E) atomicAdd(&deg[dst[i]], 1);
}

__global__ void dinv_kernel(const int* __restrict__ deg, float* __restrict__ dinv, int N) {
    int i = blockIdx.x * blockDim.x + threadIdx.x;
    if (i < N) dinv[i] = rsqrtf((float)(deg[i] + 1));  // +1 = self loop
}

// ---------------- exclusive scan (3 kernels) ----------------
__global__ __launch_bounds__(SCAN_B) void scan1_kernel(const int* __restrict__ deg,
                                                       int* __restrict__ incl,
                                                       int* __restrict__ blockSums, int N) {
    __shared__ int s[SCAN_B];
    int i = blockIdx.x * SCAN_B + threadIdx.x;
    int v = (i < N) ? deg[i] : 0;
    s[threadIdx.x] = v;
    __syncthreads();
#pragma unroll
    for (int off = 1; off < SCAN_B; off <<= 1) {
        int t = (threadIdx.x >= off) ? s[threadIdx.x - off] : 0;
        __syncthreads();
        s[threadIdx.x] += t;
        __syncthreads();
    }
    if (i < N) incl[i] = s[threadIdx.x];
    if (threadIdx.x == SCAN_B - 1) blockSums[blockIdx.x] = s[SCAN_B - 1];
}

__global__ __launch_bounds__(1024) void scan2_kernel(int* __restrict__ blockSums, int nb) {
    __shared__ int s[1024];
    int v = (threadIdx.x < nb) ? blockSums[threadIdx.x] : 0;
    s[threadIdx.x] = v;
    __syncthreads();
#pragma unroll
    for (int off = 1; off < 1024; off <<= 1) {
        int t = (threadIdx.x >= off) ? s[threadIdx.x - off] : 0;
        __syncthreads();
        s[threadIdx.x] += t;
        __syncthreads();
    }
    if (threadIdx.x < nb) blockSums[threadIdx.x] = (threadIdx.x > 0) ? s[threadIdx.x - 1] : 0;
}

__global__ void scan3_kernel(const int* __restrict__ incl, const int* __restrict__ deg,
                             const int* __restrict__ blockSums, int* __restrict__ rowstart,
                             int N, int E) {
    int i = blockIdx.x * blockDim.x + threadIdx.x;
    if (i < N) rowstart[i] = incl[i] - deg[i] + blockSums[i / SCAN_B];
    if (i == 0) rowstart[N] = E;
}

// ---------------- counting-sort scatter: elist[pos] = (src, norm) ----------------
__global__ void scatter_kernel(const int* __restrict__ src, const int* __restrict__ dst,
                               const int* __restrict__ rowstart, int* __restrict__ cursor,
                               int2* __restrict__ elist, const float* __restrict__ dinv, int E) {
    int e = blockIdx.x * blockDim.x + threadIdx.x;
    if (e >= E) return;
    int s = src[e], d = dst[e];
    int pos = rowstart[d] + atomicAdd(&cursor[d], 1);
    float nm = dinv[s] * dinv[d];
    elist[pos] = make_int2(s, __float_as_int(nm));
}

// ---------------- linear1: h = x @ W1   (x: [N,20], W1: [20,128]) ----------------
__global__ __launch_bounds__(HID) void linear1_kernel(const float* __restrict__ x,
                                                      const float* __restrict__ W,
                                                      float* __restrict__ h, int N, int IN) {
    __shared__ float Ws[20 * HID];
    __shared__ float xs[NPB1][20];
    for (int i = threadIdx.x; i < IN * HID; i += blockDim.x) Ws[i] = W[i];
    int n0 = blockIdx.x * NPB1;
    for (int i = threadIdx.x; i < NPB1 * IN; i += blockDim.x) {
        int m = i / IN, k = i % IN;
        int n = n0 + m;
        xs[m][k] = (n < N) ? x[(size_t)n * IN + k] : 0.f;
    }
    __syncthreads();
    int j = threadIdx.x;
    for (int m = 0; m < NPB1; ++m) {
        int n = n0 + m;
        if (n >= N) break;
        float acc = 0.f;
#pragma unroll 20
        for (int k = 0; k < 20; ++k) acc += xs[m][k] * Ws[k * HID + j];
        h[(size_t)n * HID + j] = acc;
    }
}

// ---------------- linear2: modest tiled SGEMM  C[N,128] = A[N,128] @ W[128,128] ----------------
// 64 nodes x 64 cols per 256-thread block; 4x4 micro-tile; single-buffer 17 KB LDS.
#define TBM 64
#define TBN 64
#define TBK 32
#define XLD (TBM + 4)   // 68: row stride in floats, keeps 16B alignment (272B)

__global__ __launch_bounds__(256) void gemm128_kernel(const float* __restrict__ A,
                                                      const float* __restrict__ W,
                                                      float* __restrict__ C, int N) {
    __shared__ float xs[TBK][XLD];       // k-major A tile
    __shared__ float wsh[TBK][TBN + 4];  // k-major W tile
    const int tid = threadIdx.x;
    const int n0 = blockIdx.x * TBM;
    const int c0 = blockIdx.y * TBN;
    const int ng = tid >> 4;   // 0..15 -> nodes ng*4..+3
    const int cg = tid & 15;   // 0..15 -> cols  cg*4..+3

    // staging indices
    const int anode = tid >> 3;  // 0..31 (+32 for r=1)
    const int af    = tid & 7;   // float4 index over 32-k chunk (contiguous 128B per node)
    const int wk    = tid >> 4;  // 0..15 (+16 for r=1)
    const int wc    = tid & 15;  // float4 index over 64 cols

    float acc[4][4] = {};

    for (int k0 = 0; k0 < HID; k0 += TBK) {
#pragma unroll
        for (int r = 0; r < 2; ++r) {
            int node = anode + r * 32;
            int gn = n0 + node;
            float4 v = make_float4(0.f, 0.f, 0.f, 0.f);
            if (gn < N) v = *(const float4*)(A + (size_t)gn * HID + k0 + af * 4);
            xs[af * 4 + 0][node] = v.x;
            xs[af * 4 + 1][node] = v.y;
            xs[af * 4 + 2][node] = v.z;
            xs[af * 4 + 3][node] = v.w;
        }
#pragma unroll
        for (int r = 0; r < 2; ++r) {
            int kk = wk + r * 16;
            *(float4*)&wsh[kk][wc * 4] =
                *(const float4*)(W + (size_t)(k0 + kk) * HID + c0 + wc * 4);
        }
        __syncthreads();
#pragma unroll
        for (int kk = 0; kk < TBK; ++kk) {
            float a[4], b[4];
            *(float4*)a = *(const float4*)&xs[kk][ng * 4];
            *(float4*)b = *(const float4*)&wsh[kk][cg * 4];
#pragma unroll
            for (int m = 0; m < 4; ++m)
#pragma unroll
                for (int n = 0; n < 4; ++n) acc[m][n] += a[m] * b[n];
        }
        __syncthreads();
    }

#pragma unroll
    for (int m = 0; m < 4; ++m) {
        int gn = n0 + ng * 4 + m;
        if (gn < N) {
            *(float4*)(C + (size_t)gn * HID + c0 + cg * 4) =
                make_float4(acc[m][0], acc[m][1], acc[m][2], acc[m][3]);
        }
    }
}

// ---------------- CSR aggregation fused with self-loop + bias + relu ----------------
__global__ __launch_bounds__(256) void csr_agg_kernel(const float* __restrict__ h,
                                                      float* __restrict__ outb,
                                                      const int* __restrict__ rowstart,
                                                      const int2* __restrict__ elist,
                                                      const float* __restrict__ dinv,
                                                      const float* __restrict__ bias,
                                                      int N) {
    int node = blockIdx.x * 2 + (threadIdx.x >> 7);
    if (node >= N) return;
    int j = threadIdx.x & 127;
    int beg = rowstart[node], end = rowstart[node + 1];
    float acc = 0.f;
    int e = beg;
    for (; e + 1 < end; e += 2) {
        int2 p0 = elist[e];
        int2 p1 = elist[e + 1];
        float a0 = h[(size_t)p0.x * HID + j];
        float a1 = h[(size_t)p1.x * HID + j];
        acc += a0 * __int_as_float(p0.y);
        acc += a1 * __int_as_float(p1.y);
    }
    if (e < end) {
        int2 p0 = elist[e];
        acc += h[(size_t)p0.x * HID + j] * __int_as_float(p0.y);
    }
    float di = dinv[node];
    float v = acc + h[(size_t)node * HID + j] * di * di + bias[j];
    outb[(size_t)node * HID + j] = fmaxf(v, 0.f);
}

// ---------------- pooling: segmented (batch is sorted) ----------------
__global__ void gstart_kernel(const int* __restrict__ batch, int* __restrict__ gstart,
                              int N, int G) {
    int g = blockIdx.x * blockDim.x + threadIdx.x;
    if (g > G) return;
    int lo = 0, hi = N;
    while (lo < hi) {
        int mid = (lo + hi) >> 1;
        if (batch[mid] < g) lo = mid + 1; else hi = mid;
    }
    gstart[g] = lo;
}

__global__ __launch_bounds__(256) void pool2_kernel(const float* __restrict__ h,
                                                    const int* __restrict__ gstart,
                                                    float* __restrict__ meanp, int G) {
    int g = blockIdx.x;
    int half = threadIdx.x >> 7;
    int j = threadIdx.x & 127;
    int beg = gstart[g], end = gstart[g + 1];
    float s = 0.f;
    for (int n = beg + half; n < end; n += 2) s += h[(size_t)n * HID + j];
    __shared__ float red[2][HID];
    red[half][j] = s;
    __syncthreads();
    if (half == 0) {
        float tot = red[0][j] + red[1][j];
        float c = (float)(end - beg);
        meanp[(size_t)g * HID + j] = tot / fmaxf(c, 1.f);
    }
}

// ---------------- classifier: out = meanp @ Wc + bc ----------------
#define TILE_G 32
__global__ __launch_bounds__(256) void classifier_kernel(const float* __restrict__ meanp,
                                                         const float* __restrict__ Wc,
                                                         const float* __restrict__ bc,
                                                         float* __restrict__ out, int G, int OUT) {
    __shared__ float ps[TILE_G * HID];  // 16 KiB
    int g0 = blockIdx.y * TILE_G;
    for (int i = threadIdx.x; i < TILE_G * HID; i += blockDim.x) {
        int g = g0 + (i >> 7);
        ps[i] = (g < G) ? meanp[(size_t)g * HID + (i & 127)] : 0.f;
    }
    __syncthreads();
    int o = blockIdx.x * blockDim.x + threadIdx.x;
    if (o >= OUT) return;
    float acc[TILE_G];
#pragma unroll
    for (int g = 0; g < TILE_G; ++g) acc[g] = 0.f;
    for (int k = 0; k < HID; ++k) {
        float w = Wc[(size_t)k * OUT + o];
#pragma unroll
        for (int g = 0; g < TILE_G; ++g) acc[g] += ps[g * HID + k] * w;
    }
    float b = bc[o];
    for (int g = 0; g < TILE_G && (g0 + g) < G; ++g)
        out[(size_t)(g0 + g) * OUT + o] = acc[g] + b;
}

// ---------------- launch ----------------
extern "C" void kernel_launch(void* const* d_in, const int* in_sizes, int n_in,
                              void* d_out, int out_size, void* d_ws, size_t ws_size,
                              hipStream_t stream) {
    const float* x  = (const float*)d_in[0];
    const void*  ei = d_in[1];
    const void*  bt = d_in[2];
    const float* W1 = (const float*)d_in[3];
    const float* b1 = (const float*)d_in[4];
    const float* W2 = (const float*)d_in[5];
    const float* b2 = (const float*)d_in[6];
    const float* Wc = (const float*)d_in[7];
    const float* bc = (const float*)d_in[8];
    float* out = (float*)d_out;

    const int N   = in_sizes[2];
    const int E   = in_sizes[1] / 2;
    const int IN  = in_sizes[0] / N;
    const int OUT = in_sizes[8];
    const int G   = out_size / OUT;

    // workspace layout
    char* ws = (char*)d_ws;
    size_t off = 0;
    auto alloc = [&](size_t bytes) {
        size_t p = off;
        off += (bytes + 255) & ~(size_t)255;
        return p;
    };
    int*   idx32    = (int*)(ws + alloc((size_t)2 * E * 4));
    int*   batch32  = (int*)(ws + alloc((size_t)N * 4));
    int*   deg      = (int*)(ws + alloc((size_t)N * 4));
    float* dinv     = (float*)(ws + alloc((size_t)N * 4));
    int*   incl     = (int*)(ws + alloc((size_t)N * 4));
    int*   rowstart = (int*)(ws + alloc((size_t)(N + 1) * 4));
    int*   cursor   = (int*)(ws + alloc((size_t)N * 4));
    int*   blockSums= (int*)(ws + alloc((size_t)1024 * 4));
    int2*  elist    = (int2*)(ws + alloc((size_t)E * 8));
    float* bufA     = (float*)(ws + alloc((size_t)N * HID * 4));
    float* bufB     = (float*)(ws + alloc((size_t)N * HID * 4));
    int*   gstart   = (int*)(ws + alloc((size_t)(G + 1) * 4));
    float* meanp    = (float*)(ws + alloc((size_t)G * HID * 4));
    int*   flag     = (int*)(ws + alloc(4));
    (void)ws_size;

    int* srcI = idx32;
    int* dstI = idx32 + E;

    const int B = 256;
    const int nb = (N + SCAN_B - 1) / SCAN_B;

    // 1. detect index dtype, convert to int32
    detect_kernel<<<1, 64, 0, stream>>>((const unsigned int*)ei, flag);
    cvt_kernel<<<(2 * E + B - 1) / B, B, 0, stream>>>(ei, idx32, 2 * E, flag);
    cvt_kernel<<<(N + B - 1) / B, B, 0, stream>>>(bt, batch32, N, flag);

    // 2. degrees (+1 self loop) -> dinv
    zero_kernel<<<256, B, 0, stream>>>((float4*)deg, (long long)N / 4);
    deg_kernel<<<(E + B - 1) / B, B, 0, stream>>>(dstI, deg, E);
    dinv_kernel<<<(N + B - 1) / B, B, 0, stream>>>(deg, dinv, N);

    // 3. CSR build: exclusive scan + counting-sort scatter
    scan1_kernel<<<nb, SCAN_B, 0, stream>>>(deg, incl, blockSums, N);
    scan2_kernel<<<1, 1024, 0, stream>>>(blockSums, nb);
    scan3_kernel<<<(N + B - 1) / B, B, 0, stream>>>(incl, deg, blockSums, rowstart, N, E);
    zero_kernel<<<256, B, 0, stream>>>((float4*)cursor, (long long)N / 4);
    scatter_kernel<<<(E + B - 1) / B, B, 0, stream>>>(srcI, dstI, rowstart, cursor, elist, dinv, E);

    // 4. graph boundaries for pooling
    gstart_kernel<<<2, 256, 0, stream>>>(batch32, gstart, N, G);

    // 5. layer 1
    linear1_kernel<<<(N + NPB1 - 1) / NPB1, HID, 0, stream>>>(x, W1, bufA, N, IN);
    csr_agg_kernel<<<(N + 1) / 2, 256, 0, stream>>>(bufA, bufB, rowstart, elist, dinv, b1, N);

    // 6. layer 2
    {
        dim3 grid((N + TBM - 1) / TBM, HID / TBN);
        gemm128_kernel<<<grid, 256, 0, stream>>>(bufB, W2, bufA, N);
    }
    csr_agg_kernel<<<(N + 1) / 2, 256, 0, stream>>>(bufA, bufB, rowstart, elist, dinv, b2, N);

    // 7. mean pool (segmented, no atomics)
    pool2_kernel<<<G, 256, 0, stream>>>(bufB, gstart, meanp, G);

    // 8. classifier
    {
        dim3 grid((OUT + 255) / 256, (G + TILE_G - 1) / TILE_G);
        classifier_kernel<<<grid, 256, 0, stream>>>(meanp, Wc, bc, out, G, OUT);
    }
}

// Round 5
// 569.812 us; speedup vs baseline: 7.4420x; 1.3340x over previous
//
#include <hip/hip_runtime.h>

#define HID 128
#define NPB1 16   // nodes per block, linear1
#define SCAN_B 256

// ---------------- index dtype detection + conversion ----------------
__global__ void detect_kernel(const unsigned int* __restrict__ p, int* __restrict__ flag) {
    if (threadIdx.x == 0 && blockIdx.x == 0) {
        int is64 = 1;
        for (int i = 0; i < 64; ++i) {
            if (p[2 * i + 1] != 0u) { is64 = 0; break; }
        }
        *flag = is64;
    }
}

__global__ void cvt_kernel(const void* __restrict__ p, int* __restrict__ out, int n,
                           const int* __restrict__ flag) {
    int i = blockIdx.x * blockDim.x + threadIdx.x;
    if (i < n) {
        out[i] = (*flag) ? (int)((const long long*)p)[i] : ((const int*)p)[i];
    }
}

// ---------------- zeroing (graph-capture-safe, no memset) ----------------
__global__ void zero_kernel(float4* __restrict__ p, long long n4) {
    long long i = (long long)blockIdx.x * blockDim.x + threadIdx.x;
    long long stride = (long long)gridDim.x * blockDim.x;
    for (; i < n4; i += stride) p[i] = make_float4(0.f, 0.f, 0.f, 0.f);
}

// ---------------- degree + dinv ----------------
__global__ void deg_kernel(const int* __restrict__ dst, int* __restrict__ deg, int E) {
    int i = blockIdx.x * blockDim.x + threadIdx.x;
    if (i < E) atomicAdd(&deg[dst[i]], 1);
}

__global__ void dinv_kernel(const int* __restrict__ deg, float* __restrict__ dinv, int N) {
    int i = blockIdx.x * blockDim.x + threadIdx.x;
    if (i < N) dinv[i] = rsqrtf((float)(deg[i] + 1));  // +1 = self loop
}

// ---------------- exclusive scan (3 kernels) ----------------
__global__ __launch_bounds__(SCAN_B) void scan1_kernel(const int* __restrict__ deg,
                                                       int* __restrict__ incl,
                                                       int* __restrict__ blockSums, int N) {
    __shared__ int s[SCAN_B];
    int i = blockIdx.x * SCAN_B + threadIdx.x;
    int v = (i < N) ? deg[i] : 0;
    s[threadIdx.x] = v;
    __syncthreads();
#pragma unroll
    for (int off = 1; off < SCAN_B; off <<= 1) {
        int t = (threadIdx.x >= off) ? s[threadIdx.x - off] : 0;
        __syncthreads();
        s[threadIdx.x] += t;
        __syncthreads();
    }
    if (i < N) incl[i] = s[threadIdx.x];
    if (threadIdx.x == SCAN_B - 1) blockSums[blockIdx.x] = s[SCAN_B - 1];
}

__global__ __launch_bounds__(1024) void scan2_kernel(int* __restrict__ blockSums, int nb) {
    __shared__ int s[1024];
    int v = (threadIdx.x < nb) ? blockSums[threadIdx.x] : 0;
    s[threadIdx.x] = v;
    __syncthreads();
#pragma unroll
    for (int off = 1; off < 1024; off <<= 1) {
        int t = (threadIdx.x >= off) ? s[threadIdx.x - off] : 0;
        __syncthreads();
        s[threadIdx.x] += t;
        __syncthreads();
    }
    if (threadIdx.x < nb) blockSums[threadIdx.x] = (threadIdx.x > 0) ? s[threadIdx.x - 1] : 0;
}

__global__ void scan3_kernel(const int* __restrict__ incl, const int* __restrict__ deg,
                             const int* __restrict__ blockSums, int* __restrict__ rowstart,
                             int N, int E) {
    int i = blockIdx.x * blockDim.x + threadIdx.x;
    if (i < N) rowstart[i] = incl[i] - deg[i] + blockSums[i / SCAN_B];
    if (i == 0) rowstart[N] = E;
}

// ---------------- counting-sort scatter: elist[pos] = (src, norm) ----------------
__global__ void scatter_kernel(const int* __restrict__ src, const int* __restrict__ dst,
                               const int* __restrict__ rowstart, int* __restrict__ cursor,
                               int2* __restrict__ elist, const float* __restrict__ dinv, int E) {
    int e = blockIdx.x * blockDim.x + threadIdx.x;
    if (e >= E) return;
    int s = src[e], d = dst[e];
    int pos = rowstart[d] + atomicAdd(&cursor[d], 1);
    float nm = dinv[s] * dinv[d];
    elist[pos] = make_int2(s, __float_as_int(nm));
}

// ---------------- 20-dim aggregation in input space (layer 1) ----------------
// z[n] = sum_e norm * x[src] + dinv[n]^2 * x[n]    (32 lanes per node, IN<=32 active)
__global__ __launch_bounds__(256) void agg20_kernel(const float* __restrict__ x,
                                                    float* __restrict__ z,
                                                    const int* __restrict__ rowstart,
                                                    const int2* __restrict__ elist,
                                                    const float* __restrict__ dinv,
                                                    int N, int IN) {
    int node = blockIdx.x * 8 + (threadIdx.x >> 5);
    if (node >= N) return;
    int j = threadIdx.x & 31;
    bool act = j < IN;
    int beg = rowstart[node], end = rowstart[node + 1];
    float acc = 0.f;
    int e = beg;
    for (; e + 1 < end; e += 2) {
        int2 p0 = elist[e];
        int2 p1 = elist[e + 1];
        float v0 = act ? x[(size_t)p0.x * IN + j] : 0.f;
        float v1 = act ? x[(size_t)p1.x * IN + j] : 0.f;
        acc += v0 * __int_as_float(p0.y);
        acc += v1 * __int_as_float(p1.y);
    }
    if (e < end) {
        int2 p0 = elist[e];
        if (act) acc += x[(size_t)p0.x * IN + j] * __int_as_float(p0.y);
    }
    if (act) {
        float di = dinv[node];
        z[(size_t)node * IN + j] = acc + x[(size_t)node * IN + j] * di * di;
    }
}

// ---------------- fused linear1: h = relu(z @ W1 + b1)  (z: [N,20]) ----------------
__global__ __launch_bounds__(HID) void linear1_kernel(const float* __restrict__ z,
                                                      const float* __restrict__ W,
                                                      const float* __restrict__ b,
                                                      float* __restrict__ h, int N, int IN) {
    __shared__ float Ws[20 * HID];
    __shared__ float xs[NPB1][20];
    for (int i = threadIdx.x; i < IN * HID; i += blockDim.x) Ws[i] = W[i];
    int n0 = blockIdx.x * NPB1;
    for (int i = threadIdx.x; i < NPB1 * IN; i += blockDim.x) {
        int m = i / IN, k = i % IN;
        int n = n0 + m;
        xs[m][k] = (n < N) ? z[(size_t)n * IN + k] : 0.f;
    }
    __syncthreads();
    int j = threadIdx.x;
    float bj = b[j];
    for (int m = 0; m < NPB1; ++m) {
        int n = n0 + m;
        if (n >= N) break;
        float acc = 0.f;
#pragma unroll 20
        for (int k = 0; k < 20; ++k) acc += xs[m][k] * Ws[k * HID + j];
        h[(size_t)n * HID + j] = fmaxf(acc + bj, 0.f);
    }
}

// ---------------- linear2: modest tiled SGEMM  C[N,128] = A[N,128] @ W[128,128] ----------------
#define TBM 64
#define TBN 64
#define TBK 32
#define XLD (TBM + 4)

__global__ __launch_bounds__(256) void gemm128_kernel(const float* __restrict__ A,
                                                      const float* __restrict__ W,
                                                      float* __restrict__ C, int N) {
    __shared__ float xs[TBK][XLD];
    __shared__ float wsh[TBK][TBN + 4];
    const int tid = threadIdx.x;
    const int n0 = blockIdx.x * TBM;
    const int c0 = blockIdx.y * TBN;
    const int ng = tid >> 4;
    const int cg = tid & 15;
    const int anode = tid >> 3;
    const int af    = tid & 7;
    const int wk    = tid >> 4;
    const int wc    = tid & 15;

    float acc[4][4] = {};

    for (int k0 = 0; k0 < HID; k0 += TBK) {
#pragma unroll
        for (int r = 0; r < 2; ++r) {
            int node = anode + r * 32;
            int gn = n0 + node;
            float4 v = make_float4(0.f, 0.f, 0.f, 0.f);
            if (gn < N) v = *(const float4*)(A + (size_t)gn * HID + k0 + af * 4);
            xs[af * 4 + 0][node] = v.x;
            xs[af * 4 + 1][node] = v.y;
            xs[af * 4 + 2][node] = v.z;
            xs[af * 4 + 3][node] = v.w;
        }
#pragma unroll
        for (int r = 0; r < 2; ++r) {
            int kk = wk + r * 16;
            *(float4*)&wsh[kk][wc * 4] =
                *(const float4*)(W + (size_t)(k0 + kk) * HID + c0 + wc * 4);
        }
        __syncthreads();
#pragma unroll
        for (int kk = 0; kk < TBK; ++kk) {
            float a[4], b[4];
            *(float4*)a = *(const float4*)&xs[kk][ng * 4];
            *(float4*)b = *(const float4*)&wsh[kk][cg * 4];
#pragma unroll
            for (int m = 0; m < 4; ++m)
#pragma unroll
                for (int n = 0; n < 4; ++n) acc[m][n] += a[m] * b[n];
        }
        __syncthreads();
    }

#pragma unroll
    for (int m = 0; m < 4; ++m) {
        int gn = n0 + ng * 4 + m;
        if (gn < N) {
            *(float4*)(C + (size_t)gn * HID + c0 + cg * 4) =
                make_float4(acc[m][0], acc[m][1], acc[m][2], acc[m][3]);
        }
    }
}

// ---------------- 128-dim CSR aggregation, float4 lanes, fused self+bias+relu ----------------
// 32-lane group per node; lane q owns cols 4q..4q+3 (16B); unroll x4 for MLP.
__global__ __launch_bounds__(256) void csr_agg4_kernel(const float* __restrict__ h,
                                                       float* __restrict__ outb,
                                                       const int* __restrict__ rowstart,
                                                       const int2* __restrict__ elist,
                                                       const float* __restrict__ dinv,
                                                       const float* __restrict__ bias,
                                                       int N) {
    int node = blockIdx.x * 8 + (threadIdx.x >> 5);
    if (node >= N) return;
    int q = threadIdx.x & 31;
    const float4* hv = (const float4*)h;
    float4 acc = make_float4(0.f, 0.f, 0.f, 0.f);
    int beg = rowstart[node], end = rowstart[node + 1];
    int e = beg;
    for (; e + 3 < end; e += 4) {
        int2 p0 = elist[e];
        int2 p1 = elist[e + 1];
        int2 p2 = elist[e + 2];
        int2 p3 = elist[e + 3];
        float4 v0 = hv[(size_t)p0.x * 32 + q];
        float4 v1 = hv[(size_t)p1.x * 32 + q];
        float4 v2 = hv[(size_t)p2.x * 32 + q];
        float4 v3 = hv[(size_t)p3.x * 32 + q];
        float n0 = __int_as_float(p0.y), n1 = __int_as_float(p1.y);
        float n2 = __int_as_float(p2.y), n3 = __int_as_float(p3.y);
        acc.x += v0.x * n0 + v1.x * n1 + v2.x * n2 + v3.x * n3;
        acc.y += v0.y * n0 + v1.y * n1 + v2.y * n2 + v3.y * n3;
        acc.z += v0.z * n0 + v1.z * n1 + v2.z * n2 + v3.z * n3;
        acc.w += v0.w * n0 + v1.w * n1 + v2.w * n2 + v3.w * n3;
    }
    for (; e < end; ++e) {
        int2 p0 = elist[e];
        float4 v0 = hv[(size_t)p0.x * 32 + q];
        float n0 = __int_as_float(p0.y);
        acc.x += v0.x * n0; acc.y += v0.y * n0; acc.z += v0.z * n0; acc.w += v0.w * n0;
    }
    float di = dinv[node];
    float dd = di * di;
    float4 self = hv[(size_t)node * 32 + q];
    float4 b4 = ((const float4*)bias)[q];
    float4 r;
    r.x = fmaxf(acc.x + self.x * dd + b4.x, 0.f);
    r.y = fmaxf(acc.y + self.y * dd + b4.y, 0.f);
    r.z = fmaxf(acc.z + self.z * dd + b4.z, 0.f);
    r.w = fmaxf(acc.w + self.w * dd + b4.w, 0.f);
    ((float4*)outb)[(size_t)node * 32 + q] = r;
}

// ---------------- pooling: segmented (batch is sorted) ----------------
__global__ void gstart_kernel(const int* __restrict__ batch, int* __restrict__ gstart,
                              int N, int G) {
    int g = blockIdx.x * blockDim.x + threadIdx.x;
    if (g > G) return;
    int lo = 0, hi = N;
    while (lo < hi) {
        int mid = (lo + hi) >> 1;
        if (batch[mid] < g) lo = mid + 1; else hi = mid;
    }
    gstart[g] = lo;
}

__global__ __launch_bounds__(256) void pool2_kernel(const float* __restrict__ h,
                                                    const int* __restrict__ gstart,
                                                    float* __restrict__ meanp, int G) {
    int g = blockIdx.x;
    int half = threadIdx.x >> 7;
    int j = threadIdx.x & 127;
    int beg = gstart[g], end = gstart[g + 1];
    float s = 0.f;
    for (int n = beg + half; n < end; n += 2) s += h[(size_t)n * HID + j];
    __shared__ float red[2][HID];
    red[half][j] = s;
    __syncthreads();
    if (half == 0) {
        float tot = red[0][j] + red[1][j];
        float c = (float)(end - beg);
        meanp[(size_t)g * HID + j] = tot / fmaxf(c, 1.f);
    }
}

// ---------------- classifier: out = meanp @ Wc + bc ----------------
#define TILE_G 32
__global__ __launch_bounds__(256) void classifier_kernel(const float* __restrict__ meanp,
                                                         const float* __restrict__ Wc,
                                                         const float* __restrict__ bc,
                                                         float* __restrict__ out, int G, int OUT) {
    __shared__ float ps[TILE_G * HID];
    int g0 = blockIdx.y * TILE_G;
    for (int i = threadIdx.x; i < TILE_G * HID; i += blockDim.x) {
        int g = g0 + (i >> 7);
        ps[i] = (g < G) ? meanp[(size_t)g * HID + (i & 127)] : 0.f;
    }
    __syncthreads();
    int o = blockIdx.x * blockDim.x + threadIdx.x;
    if (o >= OUT) return;
    float acc[TILE_G];
#pragma unroll
    for (int g = 0; g < TILE_G; ++g) acc[g] = 0.f;
    for (int k = 0; k < HID; ++k) {
        float w = Wc[(size_t)k * OUT + o];
#pragma unroll
        for (int g = 0; g < TILE_G; ++g) acc[g] += ps[g * HID + k] * w;
    }
    float b = bc[o];
    for (int g = 0; g < TILE_G && (g0 + g) < G; ++g)
        out[(size_t)(g0 + g) * OUT + o] = acc[g] + b;
}

// ---------------- launch ----------------
extern "C" void kernel_launch(void* const* d_in, const int* in_sizes, int n_in,
                              void* d_out, int out_size, void* d_ws, size_t ws_size,
                              hipStream_t stream) {
    const float* x  = (const float*)d_in[0];
    const void*  ei = d_in[1];
    const void*  bt = d_in[2];
    const float* W1 = (const float*)d_in[3];
    const float* b1 = (const float*)d_in[4];
    const float* W2 = (const float*)d_in[5];
    const float* b2 = (const float*)d_in[6];
    const float* Wc = (const float*)d_in[7];
    const float* bc = (const float*)d_in[8];
    float* out = (float*)d_out;

    const int N   = in_sizes[2];
    const int E   = in_sizes[1] / 2;
    const int IN  = in_sizes[0] / N;
    const int OUT = in_sizes[8];
    const int G   = out_size / OUT;

    // workspace layout
    char* ws = (char*)d_ws;
    size_t off = 0;
    auto alloc = [&](size_t bytes) {
        size_t p = off;
        off += (bytes + 255) & ~(size_t)255;
        return p;
    };
    int*   idx32    = (int*)(ws + alloc((size_t)2 * E * 4));
    int*   batch32  = (int*)(ws + alloc((size_t)N * 4));
    int*   deg      = (int*)(ws + alloc((size_t)N * 4));
    float* dinv     = (float*)(ws + alloc((size_t)N * 4));
    int*   incl     = (int*)(ws + alloc((size_t)N * 4));
    int*   rowstart = (int*)(ws + alloc((size_t)(N + 1) * 4));
    int*   cursor   = (int*)(ws + alloc((size_t)N * 4));
    int*   blockSums= (int*)(ws + alloc((size_t)1024 * 4));
    int2*  elist    = (int2*)(ws + alloc((size_t)E * 8));
    float* zbuf     = (float*)(ws + alloc((size_t)N * IN * 4));
    float* bufA     = (float*)(ws + alloc((size_t)N * HID * 4));
    float* bufB     = (float*)(ws + alloc((size_t)N * HID * 4));
    int*   gstart   = (int*)(ws + alloc((size_t)(G + 1) * 4));
    float* meanp    = (float*)(ws + alloc((size_t)G * HID * 4));
    int*   flag     = (int*)(ws + alloc(4));
    (void)ws_size;

    int* srcI = idx32;
    int* dstI = idx32 + E;

    const int B = 256;
    const int nb = (N + SCAN_B - 1) / SCAN_B;

    // 1. detect index dtype, convert to int32
    detect_kernel<<<1, 64, 0, stream>>>((const unsigned int*)ei, flag);
    cvt_kernel<<<(2 * E + B - 1) / B, B, 0, stream>>>(ei, idx32, 2 * E, flag);
    cvt_kernel<<<(N + B - 1) / B, B, 0, stream>>>(bt, batch32, N, flag);

    // 2. degrees (+1 self loop) -> dinv
    zero_kernel<<<256, B, 0, stream>>>((float4*)deg, (long long)N / 4);
    deg_kernel<<<(E + B - 1) / B, B, 0, stream>>>(dstI, deg, E);
    dinv_kernel<<<(N + B - 1) / B, B, 0, stream>>>(deg, dinv, N);

    // 3. CSR build: exclusive scan + counting-sort scatter
    scan1_kernel<<<nb, SCAN_B, 0, stream>>>(deg, incl, blockSums, N);
    scan2_kernel<<<1, 1024, 0, stream>>>(blockSums, nb);
    scan3_kernel<<<(N + B - 1) / B, B, 0, stream>>>(incl, deg, blockSums, rowstart, N, E);
    zero_kernel<<<256, B, 0, stream>>>((float4*)cursor, (long long)N / 4);
    scatter_kernel<<<(E + B - 1) / B, B, 0, stream>>>(srcI, dstI, rowstart, cursor, elist, dinv, E);

    // 4. graph boundaries for pooling
    gstart_kernel<<<2, 256, 0, stream>>>(batch32, gstart, N, G);

    // 5. layer 1: aggregate in 20-dim input space, then fused linear+bias+relu
    agg20_kernel<<<(N + 7) / 8, 256, 0, stream>>>(x, zbuf, rowstart, elist, dinv, N, IN);
    linear1_kernel<<<(N + NPB1 - 1) / NPB1, HID, 0, stream>>>(zbuf, W1, b1, bufA, N, IN);

    // 6. layer 2: GEMM then 128-dim aggregation (fused self+bias+relu)
    {
        dim3 grid((N + TBM - 1) / TBM, HID / TBN);
        gemm128_kernel<<<grid, 256, 0, stream>>>(bufA, W2, bufB, N);
    }
    csr_agg4_kernel<<<(N + 7) / 8, 256, 0, stream>>>(bufB, bufA, rowstart, elist, dinv, b2, N);

    // 7. mean pool (segmented, no atomics)
    pool2_kernel<<<G, 256, 0, stream>>>(bufA, gstart, meanp, G);

    // 8. classifier
    {
        dim3 grid((OUT + 255) / 256, (G + TILE_G - 1) / TILE_G);
        classifier_kernel<<<grid, 256, 0, stream>>>(meanp, Wc, bc, out, G, OUT);
    }
}